// Round 13
// baseline (23.592 us; speedup 1.0000x reference)
//
#include <hip/hip_runtime.h>
#include <hip/hip_bf16.h>

// Channel model. Serialization (decoded r0-r10, VERIFIED r11):
//   flat = [output.ravel() | H_t.ravel()] as (im, re) interleaved pairs:
//   flat[2j] = Im(z_j), flat[2j+1] = Re(z_j)
// L=8, N=512, S=64, M=82, T=5248; fd = v/3e8*3.6e9 (v=30 -> 360 Hz).
//
// r12: 23.1us with 1024 blocks -- scaling ~1/blocks => parallelism-bound.
// This round: grid (512,4) = 2048 blocks (8/CU -> 32 waves/CU cap),
// one 8-t group per thread (no imbalanced second trip).

#define CH_L 8
#define CH_N 512
#define CH_S 64
#define CH_M 82
#define CH_T 5248
#define QSPLIT 4
#define GROUPS_PER_BLK 164   // (CH_T/8) / QSPLIT

#define TWO_PI 6.283185307179586f

__device__ __forceinline__ unsigned pack_bf16x2(float lo, float hi) {
    __hip_bfloat16 hl = __float2bfloat16(lo);
    __hip_bfloat16 hh = __float2bfloat16(hi);
    unsigned short ul = *reinterpret_cast<unsigned short*>(&hl);
    unsigned short uh = *reinterpret_cast<unsigned short*>(&hh);
    return (unsigned)ul | ((unsigned)uh << 16);
}

__global__ __launch_bounds__(256) void channel_kernel(
    const float* __restrict__ xr,       // (N, T)
    const float* __restrict__ xi,       // (N, T)
    const float* __restrict__ ray_u,    // (N, L)
    const float* __restrict__ angles_u, // (L,)
    const float* __restrict__ phase_u,  // (N, L)
    const void*  __restrict__ vel_raw,  // scalar (int32/f32)
    __hip_bfloat16* __restrict__ out)
{
    const int n   = blockIdx.x;
    const int q   = blockIdx.y;          // t-quarter: 0..3
    const int tid = threadIdx.x;

    __shared__ float  s_cof[CH_L];
    __shared__ float  s_ph0[CH_L];
    __shared__ float2 s_cf[CH_L][CH_S];

    if (tid == 0) {
        const int   vi = *reinterpret_cast<const int*>(vel_raw);
        const float vf = *reinterpret_cast<const float*>(vel_raw);
        float vel;
        if (vi != 0 && vi > -1000000 && vi < 1000000) vel = (float)vi;
        else if (vf == vf && fabsf(vf) > 1e-3f && fabsf(vf) < 1e6f) vel = vf;
        else vel = 30.0f;
        const float fd = vel * (1.0f / 3.0e8f) * 3.6e9f;

        float pw[CH_L];
        float psum = 0.0f;
        #pragma unroll
        for (int l = 0; l < CH_L; ++l) { pw[l] = expf(-(float)l / 4.0f); psum += pw[l]; }
        float c[CH_L];
        #pragma unroll
        for (int l = 0; l < CH_L; ++l) {
            float u = ray_u[n * CH_L + l];
            c[l] = sqrtf(pw[l] / (2.0f * psum)) * sqrtf(-2.0f * logf(u));
        }
        for (int i = 1; i < CH_L; ++i) {           // descending insertion sort
            float v = c[i];
            int j = i - 1;
            while (j >= 0 && c[j] < v) { c[j + 1] = c[j]; --j; }
            c[j + 1] = v;
        }
        #pragma unroll
        for (int l = 0; l < CH_L; ++l) {
            s_cof[l] = c[l];
            float ang = angles_u[l] * TWO_PI;
            s_ph0[l] = TWO_PI * cosf(ang) * fd + phase_u[n * CH_L + l] * TWO_PI;
        }
    }
    __syncthreads();

    // cof_fin[l][s] = cof[l] * exp(i * ph0[l] * s / SCS)  (2 per thread)
    for (int idx = tid; idx < CH_L * CH_S; idx += 256) {
        int l = idx >> 6;
        int s = idx & (CH_S - 1);
        float ph = s_ph0[l] * ((float)s * (1.0f / 15000.0f));
        float sn, cs;
        sincosf(ph, &sn, &cs);
        float g = s_cof[l];
        s_cf[l][s] = make_float2(g * cs, g * sn);
    }
    __syncthreads();

    // H_t (only q==0 block per n)
    if (q == 0 && tid < CH_S) {
        float hr = 0.0f, hi = 0.0f;
        #pragma unroll
        for (int l = 0; l < CH_L; ++l) {
            hr += s_cf[l][tid].x;
            hi += s_cf[l][tid].y;
        }
        size_t off = (size_t)2 * CH_N * CH_T + 2 * ((size_t)n * CH_S + tid);
        *reinterpret_cast<unsigned*>(&out[off]) = pack_bf16x2(hi, hr);
    }

    if (tid >= GROUPS_PER_BLK) return;

    const float invL = 1.0f / (float)CH_L;
    const float* xrn = xr + (size_t)n * CH_T;
    const float* xin = xi + (size_t)n * CH_T;

    const int g  = q * GROUPS_PER_BLK + tid;
    const int t0 = g << 3;

    // window x[t0-8 .. t0+7] in registers
    float wr[16], wi[16];
    if (t0 == 0) {
        #pragma unroll
        for (int k = 0; k < 8; ++k) { wr[k] = 0.0f; wi[k] = 0.0f; }
        float4 a = *reinterpret_cast<const float4*>(xrn);
        float4 b = *reinterpret_cast<const float4*>(xrn + 4);
        wr[8]=a.x; wr[9]=a.y; wr[10]=a.z; wr[11]=a.w;
        wr[12]=b.x; wr[13]=b.y; wr[14]=b.z; wr[15]=b.w;
        a = *reinterpret_cast<const float4*>(xin);
        b = *reinterpret_cast<const float4*>(xin + 4);
        wi[8]=a.x; wi[9]=a.y; wi[10]=a.z; wi[11]=a.w;
        wi[12]=b.x; wi[13]=b.y; wi[14]=b.z; wi[15]=b.w;
    } else {
        const float* pr = xrn + t0 - 8;
        float4 a = *reinterpret_cast<const float4*>(pr);
        float4 b = *reinterpret_cast<const float4*>(pr + 4);
        float4 c = *reinterpret_cast<const float4*>(pr + 8);
        float4 d = *reinterpret_cast<const float4*>(pr + 12);
        wr[0]=a.x; wr[1]=a.y; wr[2]=a.z; wr[3]=a.w;
        wr[4]=b.x; wr[5]=b.y; wr[6]=b.z; wr[7]=b.w;
        wr[8]=c.x; wr[9]=c.y; wr[10]=c.z; wr[11]=c.w;
        wr[12]=d.x; wr[13]=d.y; wr[14]=d.z; wr[15]=d.w;
        const float* pi = xin + t0 - 8;
        a = *reinterpret_cast<const float4*>(pi);
        b = *reinterpret_cast<const float4*>(pi + 4);
        c = *reinterpret_cast<const float4*>(pi + 8);
        d = *reinterpret_cast<const float4*>(pi + 12);
        wi[0]=a.x; wi[1]=a.y; wi[2]=a.z; wi[3]=a.w;
        wi[4]=b.x; wi[5]=b.y; wi[6]=b.z; wi[7]=b.w;
        wi[8]=c.x; wi[9]=c.y; wi[10]=c.z; wi[11]=c.w;
        wi[12]=d.x; wi[13]=d.y; wi[14]=d.z; wi[15]=d.w;
    }

    float rr[8], ii[8];
    #pragma unroll
    for (int k = 0; k < 8; ++k) {
        const int t  = t0 + k;
        const int s0 = t / CH_M;
        const int m0 = t - s0 * CH_M;
        float ar = 0.0f, ai = 0.0f;
        #pragma unroll
        for (int l = 0; l < CH_L; ++l) {
            int s = (m0 >= l) ? s0 : (s0 - 1);   // s=-1 only when window=0
            float2 cf = s_cf[l][s];
            float vr  = wr[8 + k - l];
            float vi2 = wi[8 + k - l];
            ar += vr * cf.x - vi2 * cf.y;
            ai += vr * cf.y + vi2 * cf.x;
        }
        rr[k] = ar * invL;
        ii[k] = ai * invL;
    }

    size_t base = 2 * ((size_t)n * CH_T + t0);
    uint4 v0, v1;
    v0.x = pack_bf16x2(ii[0], rr[0]); v0.y = pack_bf16x2(ii[1], rr[1]);
    v0.z = pack_bf16x2(ii[2], rr[2]); v0.w = pack_bf16x2(ii[3], rr[3]);
    v1.x = pack_bf16x2(ii[4], rr[4]); v1.y = pack_bf16x2(ii[5], rr[5]);
    v1.z = pack_bf16x2(ii[6], rr[6]); v1.w = pack_bf16x2(ii[7], rr[7]);
    *reinterpret_cast<uint4*>(&out[base])     = v0;
    *reinterpret_cast<uint4*>(&out[base + 8]) = v1;
}

extern "C" void kernel_launch(void* const* d_in, const int* in_sizes, int n_in,
                              void* d_out, int out_size, void* d_ws, size_t ws_size,
                              hipStream_t stream) {
    const float* xr       = (const float*)d_in[0];
    const float* xi       = (const float*)d_in[1];
    const float* ray_u    = (const float*)d_in[2];
    const float* angles_u = (const float*)d_in[3];
    const float* phase_u  = (const float*)d_in[4];
    const void*  velocity = d_in[5];

    __hip_bfloat16* out = (__hip_bfloat16*)d_out;

    dim3 grid(CH_N, QSPLIT);
    channel_kernel<<<grid, 256, 0, stream>>>(xr, xi, ray_u, angles_u, phase_u,
                                             velocity, out);
}

// Round 14
// 19.852 us; speedup vs baseline: 1.1884x; 1.1884x over previous
//
#include <hip/hip_runtime.h>
#include <hip/hip_bf16.h>

// Channel model, two-kernel split.
// Serialization (decoded r0-r10, VERIFIED r11):
//   flat = [output.ravel() | H_t.ravel()] as (im, re) interleaved pairs.
// K1: per-n gains/sort/phases/sincos -> cf workspace + H_t output.
// K2: pure 8-tap complex conv, cf tile from ws via LDS (no transcendentals).

#define CH_L 8
#define CH_N 512
#define CH_S 64
#define CH_M 82
#define CH_T 5248
#define QSPLIT 4
#define GROUPS_PER_BLK 164   // (CH_T/8) / QSPLIT
#define TILE_SLOTS 17        // s in [16q-1, 16q+15]

#define TWO_PI 6.283185307179586f

__device__ __forceinline__ unsigned pack_bf16x2(float lo, float hi) {
    __hip_bfloat16 hl = __float2bfloat16(lo);
    __hip_bfloat16 hh = __float2bfloat16(hi);
    unsigned short ul = *reinterpret_cast<unsigned short*>(&hl);
    unsigned short uh = *reinterpret_cast<unsigned short*>(&hh);
    return (unsigned)ul | ((unsigned)uh << 16);
}

// ---------------- K1: coefficients + H_t ----------------
__global__ __launch_bounds__(64) void prep_kernel(
    const float* __restrict__ ray_u,    // (N, L)
    const float* __restrict__ angles_u, // (L,)
    const float* __restrict__ phase_u,  // (N, L)
    const void*  __restrict__ vel_raw,
    float2*      __restrict__ cf_ws,    // (N, L, S)
    __hip_bfloat16* __restrict__ out)
{
    const int n   = blockIdx.x;
    const int tid = threadIdx.x;

    __shared__ float s_c[CH_L];
    __shared__ float s_ph0[CH_L];

    if (tid < CH_L) {
        // psum in reference (sequential f32) order
        float psum = 0.0f;
        #pragma unroll
        for (int l = 0; l < CH_L; ++l) psum += expf(-(float)l / 4.0f);
        float pw = expf(-(float)tid / 4.0f);
        float u  = ray_u[n * CH_L + tid];
        s_c[tid] = sqrtf(pw / (2.0f * psum)) * sqrtf(-2.0f * logf(u));
    }
    __syncthreads();
    if (tid == 0) {
        float c[CH_L];
        #pragma unroll
        for (int l = 0; l < CH_L; ++l) c[l] = s_c[l];
        for (int i = 1; i < CH_L; ++i) {      // descending insertion sort
            float v = c[i];
            int j = i - 1;
            while (j >= 0 && c[j] < v) { c[j + 1] = c[j]; --j; }
            c[j + 1] = v;
        }
        #pragma unroll
        for (int l = 0; l < CH_L; ++l) s_c[l] = c[l];
    }
    __syncthreads();
    if (tid < CH_L) {
        const int   vi = *reinterpret_cast<const int*>(vel_raw);
        const float vf = *reinterpret_cast<const float*>(vel_raw);
        float vel;
        if (vi != 0 && vi > -1000000 && vi < 1000000) vel = (float)vi;
        else if (vf == vf && fabsf(vf) > 1e-3f && fabsf(vf) < 1e6f) vel = vf;
        else vel = 30.0f;
        const float fd = vel * (1.0f / 3.0e8f) * 3.6e9f;
        float ang = angles_u[tid] * TWO_PI;
        s_ph0[tid] = TWO_PI * cosf(ang) * fd + phase_u[n * CH_L + tid] * TWO_PI;
    }
    __syncthreads();

    // tid = s: all 8 taps for this s; write cf + H_t
    const float ts = (float)tid * (1.0f / 15000.0f);
    float hr = 0.0f, hi = 0.0f;
    #pragma unroll
    for (int l = 0; l < CH_L; ++l) {
        float sn, cs;
        sincosf(s_ph0[l] * ts, &sn, &cs);
        float g = s_c[l];
        float2 v = make_float2(g * cs, g * sn);
        cf_ws[((size_t)n * CH_L + l) * CH_S + tid] = v;
        hr += v.x; hi += v.y;
    }
    size_t j = (size_t)CH_N * CH_T + (size_t)n * CH_S + tid;
    *reinterpret_cast<unsigned*>(&out[2 * j]) = pack_bf16x2(hi, hr);  // im, re
}

// ---------------- K2: convolution ----------------
__global__ __launch_bounds__(256) void conv_kernel(
    const float* __restrict__ xr,       // (N, T)
    const float* __restrict__ xi,       // (N, T)
    const float2* __restrict__ cf_ws,   // (N, L, S)
    __hip_bfloat16* __restrict__ out)
{
    const int n   = blockIdx.x;
    const int q   = blockIdx.y;          // t-quarter
    const int tid = threadIdx.x;

    __shared__ float2 tile[CH_L * TILE_SLOTS];   // slot <-> s = 16q-1+slot

    if (tid < CH_L * TILE_SLOTS) {
        int l    = tid / TILE_SLOTS;
        int slot = tid - l * TILE_SLOTS;
        int s    = 16 * q - 1 + slot;
        float2 v = make_float2(0.0f, 0.0f);
        if (s >= 0) v = cf_ws[((size_t)n * CH_L + l) * CH_S + s];
        tile[tid] = v;
    }
    __syncthreads();

    if (tid >= GROUPS_PER_BLK) return;

    const float invL = 1.0f / (float)CH_L;
    const float* xrn = xr + (size_t)n * CH_T;
    const float* xin = xi + (size_t)n * CH_T;

    const int g  = q * GROUPS_PER_BLK + tid;
    const int t0 = g << 3;

    float wr[16], wi[16];
    if (t0 == 0) {
        #pragma unroll
        for (int k = 0; k < 8; ++k) { wr[k] = 0.0f; wi[k] = 0.0f; }
        float4 a = *reinterpret_cast<const float4*>(xrn);
        float4 b = *reinterpret_cast<const float4*>(xrn + 4);
        wr[8]=a.x; wr[9]=a.y; wr[10]=a.z; wr[11]=a.w;
        wr[12]=b.x; wr[13]=b.y; wr[14]=b.z; wr[15]=b.w;
        a = *reinterpret_cast<const float4*>(xin);
        b = *reinterpret_cast<const float4*>(xin + 4);
        wi[8]=a.x; wi[9]=a.y; wi[10]=a.z; wi[11]=a.w;
        wi[12]=b.x; wi[13]=b.y; wi[14]=b.z; wi[15]=b.w;
    } else {
        const float* pr = xrn + t0 - 8;
        float4 a = *reinterpret_cast<const float4*>(pr);
        float4 b = *reinterpret_cast<const float4*>(pr + 4);
        float4 c = *reinterpret_cast<const float4*>(pr + 8);
        float4 d = *reinterpret_cast<const float4*>(pr + 12);
        wr[0]=a.x; wr[1]=a.y; wr[2]=a.z; wr[3]=a.w;
        wr[4]=b.x; wr[5]=b.y; wr[6]=b.z; wr[7]=b.w;
        wr[8]=c.x; wr[9]=c.y; wr[10]=c.z; wr[11]=c.w;
        wr[12]=d.x; wr[13]=d.y; wr[14]=d.z; wr[15]=d.w;
        const float* pi = xin + t0 - 8;
        a = *reinterpret_cast<const float4*>(pi);
        b = *reinterpret_cast<const float4*>(pi + 4);
        c = *reinterpret_cast<const float4*>(pi + 8);
        d = *reinterpret_cast<const float4*>(pi + 12);
        wi[0]=a.x; wi[1]=a.y; wi[2]=a.z; wi[3]=a.w;
        wi[4]=b.x; wi[5]=b.y; wi[6]=b.z; wi[7]=b.w;
        wi[8]=c.x; wi[9]=c.y; wi[10]=c.z; wi[11]=c.w;
        wi[12]=d.x; wi[13]=d.y; wi[14]=d.z; wi[15]=d.w;
    }

    float rr[8], ii[8];
    #pragma unroll
    for (int k = 0; k < 8; ++k) {
        const int t     = t0 + k;
        const int s0    = t / CH_M;
        const int m0    = t - s0 * CH_M;
        const int slot0 = s0 - 16 * q + 1;     // slot of s0
        float ar = 0.0f, ai = 0.0f;
        #pragma unroll
        for (int l = 0; l < CH_L; ++l) {
            int slot = (m0 >= l) ? slot0 : (slot0 - 1);
            float2 cf = tile[l * TILE_SLOTS + slot];
            float vr  = wr[8 + k - l];
            float vi2 = wi[8 + k - l];
            ar += vr * cf.x - vi2 * cf.y;
            ai += vr * cf.y + vi2 * cf.x;
        }
        rr[k] = ar * invL;
        ii[k] = ai * invL;
    }

    size_t base = 2 * ((size_t)n * CH_T + t0);
    uint4 v0, v1;
    v0.x = pack_bf16x2(ii[0], rr[0]); v0.y = pack_bf16x2(ii[1], rr[1]);
    v0.z = pack_bf16x2(ii[2], rr[2]); v0.w = pack_bf16x2(ii[3], rr[3]);
    v1.x = pack_bf16x2(ii[4], rr[4]); v1.y = pack_bf16x2(ii[5], rr[5]);
    v1.z = pack_bf16x2(ii[6], rr[6]); v1.w = pack_bf16x2(ii[7], rr[7]);
    *reinterpret_cast<uint4*>(&out[base])     = v0;
    *reinterpret_cast<uint4*>(&out[base + 8]) = v1;
}

extern "C" void kernel_launch(void* const* d_in, const int* in_sizes, int n_in,
                              void* d_out, int out_size, void* d_ws, size_t ws_size,
                              hipStream_t stream) {
    const float* xr       = (const float*)d_in[0];
    const float* xi       = (const float*)d_in[1];
    const float* ray_u    = (const float*)d_in[2];
    const float* angles_u = (const float*)d_in[3];
    const float* phase_u  = (const float*)d_in[4];
    const void*  velocity = d_in[5];

    __hip_bfloat16* out = (__hip_bfloat16*)d_out;
    float2* cf_ws = (float2*)d_ws;   // 512*8*64*8 B = 2 MB

    prep_kernel<<<CH_N, 64, 0, stream>>>(ray_u, angles_u, phase_u, velocity,
                                         cf_ws, out);
    dim3 grid(CH_N, QSPLIT);
    conv_kernel<<<grid, 256, 0, stream>>>(xr, xi, cf_ws, out);
}

// Round 15
// 19.325 us; speedup vs baseline: 1.2209x; 1.0273x over previous
//
#include <hip/hip_runtime.h>
#include <hip/hip_bf16.h>

// Channel model, two-kernel split, LDS-free conv.
// Serialization (decoded r0-r10, VERIFIED r11):
//   flat = [output.ravel() | H_t.ravel()] as (im, re) interleaved pairs.
// K1: per-n gains/sort/phases/sincos -> cf workspace (N,L,S) + H_t.
// K2: flat grid, 1 group of 8 t per thread; taps span <=2 s-values =>
//     preload flo/fhi per tap and cndmask-select. No LDS, no syncthreads.

#define CH_L 8
#define CH_N 512
#define CH_S 64
#define CH_M 82
#define CH_T 5248
#define GROUPS_N 656                      // CH_T / 8
#define CONV_BLOCKS 1312                  // 512*656/256

#define TWO_PI 6.283185307179586f

__device__ __forceinline__ unsigned pack_bf16x2(float lo, float hi) {
    __hip_bfloat16 hl = __float2bfloat16(lo);
    __hip_bfloat16 hh = __float2bfloat16(hi);
    unsigned short ul = *reinterpret_cast<unsigned short*>(&hl);
    unsigned short uh = *reinterpret_cast<unsigned short*>(&hh);
    return (unsigned)ul | ((unsigned)uh << 16);
}

// ---------------- K1: coefficients + H_t ----------------
__global__ __launch_bounds__(64) void prep_kernel(
    const float* __restrict__ ray_u,    // (N, L)
    const float* __restrict__ angles_u, // (L,)
    const float* __restrict__ phase_u,  // (N, L)
    const void*  __restrict__ vel_raw,
    float2*      __restrict__ cf_ws,    // (N, L, S)
    __hip_bfloat16* __restrict__ out)
{
    const int n   = blockIdx.x;
    const int tid = threadIdx.x;

    __shared__ float s_c[CH_L];
    __shared__ float s_ph0[CH_L];

    if (tid < CH_L) {
        float psum = 0.0f;
        #pragma unroll
        for (int l = 0; l < CH_L; ++l) psum += __expf(-(float)l / 4.0f);
        float pw = __expf(-(float)tid / 4.0f);
        float u  = ray_u[n * CH_L + tid];
        s_c[tid] = sqrtf(pw / (2.0f * psum)) * sqrtf(-2.0f * __logf(u));
    }
    __syncthreads();
    if (tid == 0) {
        float c[CH_L];
        #pragma unroll
        for (int l = 0; l < CH_L; ++l) c[l] = s_c[l];
        for (int i = 1; i < CH_L; ++i) {      // descending insertion sort
            float v = c[i];
            int j = i - 1;
            while (j >= 0 && c[j] < v) { c[j + 1] = c[j]; --j; }
            c[j + 1] = v;
        }
        #pragma unroll
        for (int l = 0; l < CH_L; ++l) s_c[l] = c[l];
    }
    __syncthreads();
    if (tid < CH_L) {
        const int   vi = *reinterpret_cast<const int*>(vel_raw);
        const float vf = *reinterpret_cast<const float*>(vel_raw);
        float vel;
        if (vi != 0 && vi > -1000000 && vi < 1000000) vel = (float)vi;
        else if (vf == vf && fabsf(vf) > 1e-3f && fabsf(vf) < 1e6f) vel = vf;
        else vel = 30.0f;
        const float fd = vel * (1.0f / 3.0e8f) * 3.6e9f;
        float ang = angles_u[tid] * TWO_PI;
        s_ph0[tid] = TWO_PI * __cosf(ang) * fd + phase_u[n * CH_L + tid] * TWO_PI;
    }
    __syncthreads();

    // tid = s: all 8 taps for this s; write cf + H_t
    const float ts = (float)tid * (1.0f / 15000.0f);
    float hr = 0.0f, hi = 0.0f;
    #pragma unroll
    for (int l = 0; l < CH_L; ++l) {
        float sn, cs;
        __sincosf(s_ph0[l] * ts, &sn, &cs);
        float g = s_c[l];
        float2 v = make_float2(g * cs, g * sn);
        cf_ws[((size_t)n * CH_L + l) * CH_S + tid] = v;
        hr += v.x; hi += v.y;
    }
    size_t j = (size_t)CH_N * CH_T + (size_t)n * CH_S + tid;
    *reinterpret_cast<unsigned*>(&out[2 * j]) = pack_bf16x2(hi, hr);  // im, re
}

// ---------------- K2: convolution (no LDS) ----------------
__global__ __launch_bounds__(256) void conv_kernel(
    const float* __restrict__ xr,       // (N, T)
    const float* __restrict__ xi,       // (N, T)
    const float2* __restrict__ cf_ws,   // (N, L, S)
    __hip_bfloat16* __restrict__ out)
{
    const int g  = blockIdx.x * 256 + threadIdx.x;   // global group id
    const int n  = g / GROUPS_N;
    const int gg = g - n * GROUPS_N;
    const int t0 = gg << 3;

    const int s00 = t0 / CH_M;
    const int m00 = t0 - s00 * CH_M;
    const int sHi = s00 + ((m00 + 7) >= CH_M ? 1 : 0);
    int sLo = s00 - (m00 < 7 ? 1 : 0);
    if (sLo < 0) sLo = 0;                 // t0=0 dip: window is zero anyway

    // taps span at most 2 s-values: preload both cf rows into registers
    const float2* cfn = cf_ws + (size_t)n * (CH_L * CH_S);
    float2 flo[CH_L], fhi[CH_L];
    #pragma unroll
    for (int l = 0; l < CH_L; ++l) {
        flo[l] = cfn[(l << 6) + sLo];
        fhi[l] = cfn[(l << 6) + sHi];
    }

    const float* xrn = xr + (size_t)n * CH_T;
    const float* xin = xi + (size_t)n * CH_T;

    // window x[t0-8 .. t0+7] in registers
    float wr[16], wi[16];
    if (t0 == 0) {
        #pragma unroll
        for (int k = 0; k < 8; ++k) { wr[k] = 0.0f; wi[k] = 0.0f; }
        float4 a = *reinterpret_cast<const float4*>(xrn);
        float4 b = *reinterpret_cast<const float4*>(xrn + 4);
        wr[8]=a.x; wr[9]=a.y; wr[10]=a.z; wr[11]=a.w;
        wr[12]=b.x; wr[13]=b.y; wr[14]=b.z; wr[15]=b.w;
        a = *reinterpret_cast<const float4*>(xin);
        b = *reinterpret_cast<const float4*>(xin + 4);
        wi[8]=a.x; wi[9]=a.y; wi[10]=a.z; wi[11]=a.w;
        wi[12]=b.x; wi[13]=b.y; wi[14]=b.z; wi[15]=b.w;
    } else {
        const float* pr = xrn + t0 - 8;
        float4 a = *reinterpret_cast<const float4*>(pr);
        float4 b = *reinterpret_cast<const float4*>(pr + 4);
        float4 c = *reinterpret_cast<const float4*>(pr + 8);
        float4 d = *reinterpret_cast<const float4*>(pr + 12);
        wr[0]=a.x; wr[1]=a.y; wr[2]=a.z; wr[3]=a.w;
        wr[4]=b.x; wr[5]=b.y; wr[6]=b.z; wr[7]=b.w;
        wr[8]=c.x; wr[9]=c.y; wr[10]=c.z; wr[11]=c.w;
        wr[12]=d.x; wr[13]=d.y; wr[14]=d.z; wr[15]=d.w;
        const float* pi = xin + t0 - 8;
        a = *reinterpret_cast<const float4*>(pi);
        b = *reinterpret_cast<const float4*>(pi + 4);
        c = *reinterpret_cast<const float4*>(pi + 8);
        d = *reinterpret_cast<const float4*>(pi + 12);
        wi[0]=a.x; wi[1]=a.y; wi[2]=a.z; wi[3]=a.w;
        wi[4]=b.x; wi[5]=b.y; wi[6]=b.z; wi[7]=b.w;
        wi[8]=c.x; wi[9]=c.y; wi[10]=c.z; wi[11]=c.w;
        wi[12]=d.x; wi[13]=d.y; wi[14]=d.z; wi[15]=d.w;
    }

    float rr[8], ii[8];
    #pragma unroll
    for (int k = 0; k < 8; ++k) {
        int m = m00 + k;
        int cross = (m >= CH_M) ? 1 : 0;
        m -= cross * CH_M;
        const int  s0   = s00 + cross;
        const bool hi_t = (s0 == sHi);
        float ar = 0.0f, ai = 0.0f;
        #pragma unroll
        for (int l = 0; l < CH_L; ++l) {
            float2 cf = (hi_t && (m >= l)) ? fhi[l] : flo[l];
            float vr  = wr[8 + k - l];
            float vi2 = wi[8 + k - l];
            ar += vr * cf.x - vi2 * cf.y;
            ai += vr * cf.y + vi2 * cf.x;
        }
        rr[k] = ar * 0.125f;
        ii[k] = ai * 0.125f;
    }

    size_t base = 2 * ((size_t)n * CH_T + t0);
    uint4 v0, v1;
    v0.x = pack_bf16x2(ii[0], rr[0]); v0.y = pack_bf16x2(ii[1], rr[1]);
    v0.z = pack_bf16x2(ii[2], rr[2]); v0.w = pack_bf16x2(ii[3], rr[3]);
    v1.x = pack_bf16x2(ii[4], rr[4]); v1.y = pack_bf16x2(ii[5], rr[5]);
    v1.z = pack_bf16x2(ii[6], rr[6]); v1.w = pack_bf16x2(ii[7], rr[7]);
    *reinterpret_cast<uint4*>(&out[base])     = v0;
    *reinterpret_cast<uint4*>(&out[base + 8]) = v1;
}

extern "C" void kernel_launch(void* const* d_in, const int* in_sizes, int n_in,
                              void* d_out, int out_size, void* d_ws, size_t ws_size,
                              hipStream_t stream) {
    const float* xr       = (const float*)d_in[0];
    const float* xi       = (const float*)d_in[1];
    const float* ray_u    = (const float*)d_in[2];
    const float* angles_u = (const float*)d_in[3];
    const float* phase_u  = (const float*)d_in[4];
    const void*  velocity = d_in[5];

    __hip_bfloat16* out = (__hip_bfloat16*)d_out;
    float2* cf_ws = (float2*)d_ws;   // 512*8*64*8 B = 2 MB

    prep_kernel<<<CH_N, 64, 0, stream>>>(ray_u, angles_u, phase_u, velocity,
                                         cf_ws, out);
    conv_kernel<<<CONV_BLOCKS, 256, 0, stream>>>(xr, xi, cf_ws, out);
}

// Round 16
// 17.343 us; speedup vs baseline: 1.3604x; 1.1143x over previous
//
#include <hip/hip_runtime.h>
#include <hip/hip_bf16.h>

// Channel model, FUSED single kernel.
// Serialization (decoded r0-r10, VERIFIED r11+):
//   flat = [output.ravel() | H_t.ravel()] as (im, re) interleaved pairs:
//   flat[2j] = Im(z_j), flat[2j+1] = Re(z_j)
// Per block (n, q): parallel setup (rank-sort gains, ph0, 17x8 cf tile via
// one __sincosf per thread), distributed H_t (s in [16q,16q+16)), then
// register-window 8-tap conv, one 8-t group per thread.

#define CH_L 8
#define CH_N 512
#define CH_S 64
#define CH_M 82
#define CH_T 5248
#define QSPLIT 4
#define GROUPS_PER_BLK 164   // (CH_T/8)/QSPLIT ; t0 = 1312q + 8*tid, 1312 = 16*82
#define TILE_SLOTS 17        // slot <-> s = 16q - 1 + slot

#define TWO_PI 6.283185307179586f

__device__ __forceinline__ unsigned pack_bf16x2(float lo, float hi) {
    __hip_bfloat16 hl = __float2bfloat16(lo);
    __hip_bfloat16 hh = __float2bfloat16(hi);
    unsigned short ul = *reinterpret_cast<unsigned short*>(&hl);
    unsigned short uh = *reinterpret_cast<unsigned short*>(&hh);
    return (unsigned)ul | ((unsigned)uh << 16);
}

__global__ __launch_bounds__(256) void channel_fused(
    const float* __restrict__ xr,       // (N, T)
    const float* __restrict__ xi,       // (N, T)
    const float* __restrict__ ray_u,    // (N, L)
    const float* __restrict__ angles_u, // (L,)
    const float* __restrict__ phase_u,  // (N, L)
    const void*  __restrict__ vel_raw,  // scalar (int32/f32)
    __hip_bfloat16* __restrict__ out)
{
    const int n   = blockIdx.x;
    const int q   = blockIdx.y;
    const int tid = threadIdx.x;

    __shared__ float  s_raw[CH_L];
    __shared__ float  s_srt[CH_L];
    __shared__ float  s_ph0[CH_L];
    __shared__ float2 tile[CH_L][TILE_SLOTS];

    if (tid < CH_L) {
        // gains (unsorted)
        float psum = 0.0f;
        #pragma unroll
        for (int l = 0; l < CH_L; ++l) psum += __expf(-(float)l / 4.0f);
        float pw = __expf(-(float)tid / 4.0f);
        float u  = ray_u[n * CH_L + tid];
        s_raw[tid] = sqrtf(pw / (2.0f * psum)) * sqrtf(-2.0f * __logf(u));

        // Doppler ph0 (independent of sort)
        const int   vi = *reinterpret_cast<const int*>(vel_raw);
        const float vf = *reinterpret_cast<const float*>(vel_raw);
        float vel;
        if (vi != 0 && vi > -1000000 && vi < 1000000) vel = (float)vi;
        else if (vf == vf && fabsf(vf) > 1e-3f && fabsf(vf) < 1e6f) vel = vf;
        else vel = 30.0f;
        const float fd = vel * (1.0f / 3.0e8f) * 3.6e9f;
        s_ph0[tid] = TWO_PI * __cosf(angles_u[tid] * TWO_PI) * fd
                   + phase_u[n * CH_L + tid] * TWO_PI;
    }
    __syncthreads();
    if (tid < CH_L) {
        // descending rank-sort (stable): 8 comparisons per thread
        float mine = s_raw[tid];
        int rank = 0;
        #pragma unroll
        for (int j = 0; j < CH_L; ++j) {
            float o = s_raw[j];
            rank += (o > mine) || (o == mine && j < tid);
        }
        s_srt[rank] = mine;
    }
    __syncthreads();
    if (tid < CH_L * TILE_SLOTS) {
        int l    = tid / TILE_SLOTS;
        int slot = tid - l * TILE_SLOTS;
        int s    = 16 * q - 1 + slot;
        float2 v = make_float2(0.0f, 0.0f);
        if (s >= 0) {
            float sn, cs;
            __sincosf(s_ph0[l] * ((float)s * (1.0f / 15000.0f)), &sn, &cs);
            float g = s_srt[l];
            v = make_float2(g * cs, g * sn);
        }
        tile[l][slot] = v;
    }
    __syncthreads();

    // H_t: this block covers s = 16q .. 16q+15 (tile slots 1..16)
    if (tid < 16) {
        float hr = 0.0f, hi = 0.0f;
        #pragma unroll
        for (int l = 0; l < CH_L; ++l) {
            float2 v = tile[l][tid + 1];
            hr += v.x; hi += v.y;
        }
        size_t j = (size_t)CH_N * CH_T + (size_t)n * CH_S + 16 * q + tid;
        *reinterpret_cast<unsigned*>(&out[2 * j]) = pack_bf16x2(hi, hr);
    }

    if (tid >= GROUPS_PER_BLK) return;

    const int t0  = 1312 * q + (tid << 3);
    const int s00 = t0 / CH_M;
    const int m00 = t0 - s00 * CH_M;
    const int sHi = s00 + ((m00 + 7) >= CH_M ? 1 : 0);
    const int sLo = s00 - (m00 < 7 ? 1 : 0);          // may be -1 at t0=0 (zero window)
    const int slotLo = sLo - 16 * q + 1;
    const int slotHi = sHi - 16 * q + 1;

    float2 flo[CH_L], fhi[CH_L];
    #pragma unroll
    for (int l = 0; l < CH_L; ++l) {
        flo[l] = tile[l][slotLo];
        fhi[l] = tile[l][slotHi];
    }

    const float* xrn = xr + (size_t)n * CH_T;
    const float* xin = xi + (size_t)n * CH_T;

    // window x[t0-8 .. t0+7] in registers
    float wr[16], wi[16];
    if (t0 == 0) {
        #pragma unroll
        for (int k = 0; k < 8; ++k) { wr[k] = 0.0f; wi[k] = 0.0f; }
        float4 a = *reinterpret_cast<const float4*>(xrn);
        float4 b = *reinterpret_cast<const float4*>(xrn + 4);
        wr[8]=a.x; wr[9]=a.y; wr[10]=a.z; wr[11]=a.w;
        wr[12]=b.x; wr[13]=b.y; wr[14]=b.z; wr[15]=b.w;
        a = *reinterpret_cast<const float4*>(xin);
        b = *reinterpret_cast<const float4*>(xin + 4);
        wi[8]=a.x; wi[9]=a.y; wi[10]=a.z; wi[11]=a.w;
        wi[12]=b.x; wi[13]=b.y; wi[14]=b.z; wi[15]=b.w;
    } else {
        const float* pr = xrn + t0 - 8;
        float4 a = *reinterpret_cast<const float4*>(pr);
        float4 b = *reinterpret_cast<const float4*>(pr + 4);
        float4 c = *reinterpret_cast<const float4*>(pr + 8);
        float4 d = *reinterpret_cast<const float4*>(pr + 12);
        wr[0]=a.x; wr[1]=a.y; wr[2]=a.z; wr[3]=a.w;
        wr[4]=b.x; wr[5]=b.y; wr[6]=b.z; wr[7]=b.w;
        wr[8]=c.x; wr[9]=c.y; wr[10]=c.z; wr[11]=c.w;
        wr[12]=d.x; wr[13]=d.y; wr[14]=d.z; wr[15]=d.w;
        const float* pi = xin + t0 - 8;
        a = *reinterpret_cast<const float4*>(pi);
        b = *reinterpret_cast<const float4*>(pi + 4);
        c = *reinterpret_cast<const float4*>(pi + 8);
        d = *reinterpret_cast<const float4*>(pi + 12);
        wi[0]=a.x; wi[1]=a.y; wi[2]=a.z; wi[3]=a.w;
        wi[4]=b.x; wi[5]=b.y; wi[6]=b.z; wi[7]=b.w;
        wi[8]=c.x; wi[9]=c.y; wi[10]=c.z; wi[11]=c.w;
        wi[12]=d.x; wi[13]=d.y; wi[14]=d.z; wi[15]=d.w;
    }

    float rr[8], ii[8];
    #pragma unroll
    for (int k = 0; k < 8; ++k) {
        int m = m00 + k;
        int cross = (m >= CH_M) ? 1 : 0;
        m -= cross * CH_M;
        const bool hi_t = ((s00 + cross) == sHi);
        float ar = 0.0f, ai = 0.0f;
        #pragma unroll
        for (int l = 0; l < CH_L; ++l) {
            float2 cf = (hi_t && (m >= l)) ? fhi[l] : flo[l];
            float vr  = wr[8 + k - l];
            float vi2 = wi[8 + k - l];
            ar += vr * cf.x - vi2 * cf.y;
            ai += vr * cf.y + vi2 * cf.x;
        }
        rr[k] = ar * 0.125f;
        ii[k] = ai * 0.125f;
    }

    size_t base = 2 * ((size_t)n * CH_T + t0);
    uint4 v0, v1;
    v0.x = pack_bf16x2(ii[0], rr[0]); v0.y = pack_bf16x2(ii[1], rr[1]);
    v0.z = pack_bf16x2(ii[2], rr[2]); v0.w = pack_bf16x2(ii[3], rr[3]);
    v1.x = pack_bf16x2(ii[4], rr[4]); v1.y = pack_bf16x2(ii[5], rr[5]);
    v1.z = pack_bf16x2(ii[6], rr[6]); v1.w = pack_bf16x2(ii[7], rr[7]);
    *reinterpret_cast<uint4*>(&out[base])     = v0;
    *reinterpret_cast<uint4*>(&out[base + 8]) = v1;
}

extern "C" void kernel_launch(void* const* d_in, const int* in_sizes, int n_in,
                              void* d_out, int out_size, void* d_ws, size_t ws_size,
                              hipStream_t stream) {
    const float* xr       = (const float*)d_in[0];
    const float* xi       = (const float*)d_in[1];
    const float* ray_u    = (const float*)d_in[2];
    const float* angles_u = (const float*)d_in[3];
    const float* phase_u  = (const float*)d_in[4];
    const void*  velocity = d_in[5];

    __hip_bfloat16* out = (__hip_bfloat16*)d_out;

    dim3 grid(CH_N, QSPLIT);
    channel_fused<<<grid, 256, 0, stream>>>(xr, xi, ray_u, angles_u, phase_u,
                                            velocity, out);
}

// Round 17
// 16.343 us; speedup vs baseline: 1.4436x; 1.0611x over previous
//
#include <hip/hip_runtime.h>
#include <hip/hip_bf16.h>

// Channel model, FUSED single kernel.
// Serialization (decoded r0-r10, VERIFIED r11+):
//   flat = [output.ravel() | H_t.ravel()] as (im, re) interleaved pairs:
//   flat[2j] = Im(z_j), flat[2j+1] = Re(z_j)
// This round: tap-select reduced to w-threshold (k-l >= delta), immediate
// bf16 packing (lower VGPR), otherwise identical to r16's verified kernel.

#define CH_L 8
#define CH_N 512
#define CH_S 64
#define CH_M 82
#define CH_T 5248
#define QSPLIT 4
#define GROUPS_PER_BLK 164   // (CH_T/8)/QSPLIT ; t0 = 1312q + 8*tid
#define TILE_SLOTS 17        // slot <-> s = 16q - 1 + slot

#define TWO_PI 6.283185307179586f

__device__ __forceinline__ unsigned pack_bf16x2(float lo, float hi) {
    __hip_bfloat16 hl = __float2bfloat16(lo);
    __hip_bfloat16 hh = __float2bfloat16(hi);
    unsigned short ul = *reinterpret_cast<unsigned short*>(&hl);
    unsigned short uh = *reinterpret_cast<unsigned short*>(&hh);
    return (unsigned)ul | ((unsigned)uh << 16);
}

__global__ __launch_bounds__(256) void channel_fused(
    const float* __restrict__ xr,       // (N, T)
    const float* __restrict__ xi,       // (N, T)
    const float* __restrict__ ray_u,    // (N, L)
    const float* __restrict__ angles_u, // (L,)
    const float* __restrict__ phase_u,  // (N, L)
    const void*  __restrict__ vel_raw,  // scalar (int32/f32)
    __hip_bfloat16* __restrict__ out)
{
    const int n   = blockIdx.x;
    const int q   = blockIdx.y;
    const int tid = threadIdx.x;

    __shared__ float  s_raw[CH_L];
    __shared__ float  s_srt[CH_L];
    __shared__ float  s_ph0[CH_L];
    __shared__ float2 tile[CH_L][TILE_SLOTS];

    if (tid < CH_L) {
        float psum = 0.0f;
        #pragma unroll
        for (int l = 0; l < CH_L; ++l) psum += __expf(-(float)l / 4.0f);
        float pw = __expf(-(float)tid / 4.0f);
        float u  = ray_u[n * CH_L + tid];
        s_raw[tid] = sqrtf(pw / (2.0f * psum)) * sqrtf(-2.0f * __logf(u));

        const int   vi = *reinterpret_cast<const int*>(vel_raw);
        const float vf = *reinterpret_cast<const float*>(vel_raw);
        float vel;
        if (vi != 0 && vi > -1000000 && vi < 1000000) vel = (float)vi;
        else if (vf == vf && fabsf(vf) > 1e-3f && fabsf(vf) < 1e6f) vel = vf;
        else vel = 30.0f;
        const float fd = vel * (1.0f / 3.0e8f) * 3.6e9f;
        s_ph0[tid] = TWO_PI * __cosf(angles_u[tid] * TWO_PI) * fd
                   + phase_u[n * CH_L + tid] * TWO_PI;
    }
    __syncthreads();
    if (tid < CH_L) {
        // descending rank-sort (stable): 8 comparisons per thread
        float mine = s_raw[tid];
        int rank = 0;
        #pragma unroll
        for (int j = 0; j < CH_L; ++j) {
            float o = s_raw[j];
            rank += (o > mine) || (o == mine && j < tid);
        }
        s_srt[rank] = mine;
    }
    __syncthreads();
    if (tid < CH_L * TILE_SLOTS) {
        int l    = tid / TILE_SLOTS;
        int slot = tid - l * TILE_SLOTS;
        int s    = 16 * q - 1 + slot;
        float2 v = make_float2(0.0f, 0.0f);
        if (s >= 0) {
            float sn, cs;
            __sincosf(s_ph0[l] * ((float)s * (1.0f / 15000.0f)), &sn, &cs);
            float g = s_srt[l];
            v = make_float2(g * cs, g * sn);
        }
        tile[l][slot] = v;
    }
    __syncthreads();

    // H_t: this block covers s = 16q .. 16q+15 (tile slots 1..16)
    if (tid < 16) {
        float hr = 0.0f, hi = 0.0f;
        #pragma unroll
        for (int l = 0; l < CH_L; ++l) {
            float2 v = tile[l][tid + 1];
            hr += v.x; hi += v.y;
        }
        size_t j = (size_t)CH_N * CH_T + (size_t)n * CH_S + 16 * q + tid;
        *reinterpret_cast<unsigned*>(&out[2 * j]) = pack_bf16x2(hi, hr);
    }

    if (tid >= GROUPS_PER_BLK) return;

    const int t0  = 1312 * q + (tid << 3);
    const int s00 = t0 / CH_M;
    const int m00 = t0 - s00 * CH_M;
    const int sHi = s00 + ((m00 + 7) >= CH_M ? 1 : 0);
    const int sLo = s00 - (m00 < 7 ? 1 : 0);          // -1 at t0=0 -> zeroed slot 0
    const int slotLo = sLo - 16 * q + 1;
    const int slotHi = sHi - 16 * q + 1;

    // Tap-row select reduces to (k - l >= delta):
    //   m00 in [7,74]  : sLo==sHi, delta=-m00 -> always "hi" (== lo)     [case A]
    //   m00 >= 75      : delta = 82-m00 = kc; hi iff k-l >= kc           [case B]
    //   m00 <  7       : delta = -m00;   hi iff k >= l-m00               [case C]
    const int delta = (m00 >= 75) ? (CH_M - m00) : (-m00);
    int thr[CH_L];
    #pragma unroll
    for (int l = 0; l < CH_L; ++l) thr[l] = l + delta;

    float2 flo[CH_L], fhi[CH_L];
    #pragma unroll
    for (int l = 0; l < CH_L; ++l) {
        flo[l] = tile[l][slotLo];
        fhi[l] = tile[l][slotHi];
    }

    const float* xrn = xr + (size_t)n * CH_T;
    const float* xin = xi + (size_t)n * CH_T;

    // window x[t0-8 .. t0+7] in registers
    float wr[16], wi[16];
    if (t0 == 0) {
        #pragma unroll
        for (int k = 0; k < 8; ++k) { wr[k] = 0.0f; wi[k] = 0.0f; }
        float4 a = *reinterpret_cast<const float4*>(xrn);
        float4 b = *reinterpret_cast<const float4*>(xrn + 4);
        wr[8]=a.x; wr[9]=a.y; wr[10]=a.z; wr[11]=a.w;
        wr[12]=b.x; wr[13]=b.y; wr[14]=b.z; wr[15]=b.w;
        a = *reinterpret_cast<const float4*>(xin);
        b = *reinterpret_cast<const float4*>(xin + 4);
        wi[8]=a.x; wi[9]=a.y; wi[10]=a.z; wi[11]=a.w;
        wi[12]=b.x; wi[13]=b.y; wi[14]=b.z; wi[15]=b.w;
    } else {
        const float* pr = xrn + t0 - 8;
        float4 a = *reinterpret_cast<const float4*>(pr);
        float4 b = *reinterpret_cast<const float4*>(pr + 4);
        float4 c = *reinterpret_cast<const float4*>(pr + 8);
        float4 d = *reinterpret_cast<const float4*>(pr + 12);
        wr[0]=a.x; wr[1]=a.y; wr[2]=a.z; wr[3]=a.w;
        wr[4]=b.x; wr[5]=b.y; wr[6]=b.z; wr[7]=b.w;
        wr[8]=c.x; wr[9]=c.y; wr[10]=c.z; wr[11]=c.w;
        wr[12]=d.x; wr[13]=d.y; wr[14]=d.z; wr[15]=d.w;
        const float* pi = xin + t0 - 8;
        a = *reinterpret_cast<const float4*>(pi);
        b = *reinterpret_cast<const float4*>(pi + 4);
        c = *reinterpret_cast<const float4*>(pi + 8);
        d = *reinterpret_cast<const float4*>(pi + 12);
        wi[0]=a.x; wi[1]=a.y; wi[2]=a.z; wi[3]=a.w;
        wi[4]=b.x; wi[5]=b.y; wi[6]=b.z; wi[7]=b.w;
        wi[8]=c.x; wi[9]=c.y; wi[10]=c.z; wi[11]=c.w;
        wi[12]=d.x; wi[13]=d.y; wi[14]=d.z; wi[15]=d.w;
    }

    uint4 v0, v1;
    #pragma unroll
    for (int k = 0; k < 8; ++k) {
        float ar = 0.0f, ai = 0.0f;
        #pragma unroll
        for (int l = 0; l < CH_L; ++l) {
            const bool hi = (k >= thr[l]);
            float cfx = hi ? fhi[l].x : flo[l].x;
            float cfy = hi ? fhi[l].y : flo[l].y;
            float vr  = wr[8 + k - l];
            float vi2 = wi[8 + k - l];
            ar += vr * cfx - vi2 * cfy;
            ai += vr * cfy + vi2 * cfx;
        }
        unsigned p = pack_bf16x2(ai * 0.125f, ar * 0.125f);
        if (k < 4) (&v0.x)[k] = p; else (&v1.x)[k - 4] = p;
    }

    size_t base = 2 * ((size_t)n * CH_T + t0);
    *reinterpret_cast<uint4*>(&out[base])     = v0;
    *reinterpret_cast<uint4*>(&out[base + 8]) = v1;
}

extern "C" void kernel_launch(void* const* d_in, const int* in_sizes, int n_in,
                              void* d_out, int out_size, void* d_ws, size_t ws_size,
                              hipStream_t stream) {
    const float* xr       = (const float*)d_in[0];
    const float* xi       = (const float*)d_in[1];
    const float* ray_u    = (const float*)d_in[2];
    const float* angles_u = (const float*)d_in[3];
    const float* phase_u  = (const float*)d_in[4];
    const void*  velocity = d_in[5];

    __hip_bfloat16* out = (__hip_bfloat16*)d_out;

    dim3 grid(CH_N, QSPLIT);
    channel_fused<<<grid, 256, 0, stream>>>(xr, xi, ray_u, angles_u, phase_u,
                                            velocity, out);
}

// Round 18
// 16.123 us; speedup vs baseline: 1.4633x; 1.0137x over previous
//
#include <hip/hip_runtime.h>
#include <hip/hip_bf16.h>

// Channel model, FUSED single kernel.
// Serialization (decoded r0-r10, VERIFIED r11+):
//   flat = [output.ravel() | H_t.ravel()] as (im, re) interleaved pairs:
//   flat[2j] = Im(z_j), flat[2j+1] = Re(z_j)
// r18: block 192 (3 waves) instead of 256 -- conv uses 164 lanes (85% vs 64%),
// less wave parking. Logic byte-identical to r17.

#define CH_L 8
#define CH_N 512
#define CH_S 64
#define CH_M 82
#define CH_T 5248
#define QSPLIT 4
#define GROUPS_PER_BLK 164   // (CH_T/8)/QSPLIT ; t0 = 1312q + 8*tid
#define TILE_SLOTS 17        // slot <-> s = 16q - 1 + slot
#define BLK 192

#define TWO_PI 6.283185307179586f

__device__ __forceinline__ unsigned pack_bf16x2(float lo, float hi) {
    __hip_bfloat16 hl = __float2bfloat16(lo);
    __hip_bfloat16 hh = __float2bfloat16(hi);
    unsigned short ul = *reinterpret_cast<unsigned short*>(&hl);
    unsigned short uh = *reinterpret_cast<unsigned short*>(&hh);
    return (unsigned)ul | ((unsigned)uh << 16);
}

__global__ __launch_bounds__(BLK) void channel_fused(
    const float* __restrict__ xr,       // (N, T)
    const float* __restrict__ xi,       // (N, T)
    const float* __restrict__ ray_u,    // (N, L)
    const float* __restrict__ angles_u, // (L,)
    const float* __restrict__ phase_u,  // (N, L)
    const void*  __restrict__ vel_raw,  // scalar (int32/f32)
    __hip_bfloat16* __restrict__ out)
{
    const int n   = blockIdx.x;
    const int q   = blockIdx.y;
    const int tid = threadIdx.x;

    __shared__ float  s_raw[CH_L];
    __shared__ float  s_srt[CH_L];
    __shared__ float  s_ph0[CH_L];
    __shared__ float2 tile[CH_L][TILE_SLOTS];

    if (tid < CH_L) {
        float psum = 0.0f;
        #pragma unroll
        for (int l = 0; l < CH_L; ++l) psum += __expf(-(float)l / 4.0f);
        float pw = __expf(-(float)tid / 4.0f);
        float u  = ray_u[n * CH_L + tid];
        s_raw[tid] = sqrtf(pw / (2.0f * psum)) * sqrtf(-2.0f * __logf(u));

        const int   vi = *reinterpret_cast<const int*>(vel_raw);
        const float vf = *reinterpret_cast<const float*>(vel_raw);
        float vel;
        if (vi != 0 && vi > -1000000 && vi < 1000000) vel = (float)vi;
        else if (vf == vf && fabsf(vf) > 1e-3f && fabsf(vf) < 1e6f) vel = vf;
        else vel = 30.0f;
        const float fd = vel * (1.0f / 3.0e8f) * 3.6e9f;
        s_ph0[tid] = TWO_PI * __cosf(angles_u[tid] * TWO_PI) * fd
                   + phase_u[n * CH_L + tid] * TWO_PI;
    }
    __syncthreads();
    if (tid < CH_L) {
        // descending rank-sort (stable): 8 comparisons per thread
        float mine = s_raw[tid];
        int rank = 0;
        #pragma unroll
        for (int j = 0; j < CH_L; ++j) {
            float o = s_raw[j];
            rank += (o > mine) || (o == mine && j < tid);
        }
        s_srt[rank] = mine;
    }
    __syncthreads();
    if (tid < CH_L * TILE_SLOTS) {
        int l    = tid / TILE_SLOTS;
        int slot = tid - l * TILE_SLOTS;
        int s    = 16 * q - 1 + slot;
        float2 v = make_float2(0.0f, 0.0f);
        if (s >= 0) {
            float sn, cs;
            __sincosf(s_ph0[l] * ((float)s * (1.0f / 15000.0f)), &sn, &cs);
            float g = s_srt[l];
            v = make_float2(g * cs, g * sn);
        }
        tile[l][slot] = v;
    }
    __syncthreads();

    // H_t: this block covers s = 16q .. 16q+15 (tile slots 1..16)
    if (tid < 16) {
        float hr = 0.0f, hi = 0.0f;
        #pragma unroll
        for (int l = 0; l < CH_L; ++l) {
            float2 v = tile[l][tid + 1];
            hr += v.x; hi += v.y;
        }
        size_t j = (size_t)CH_N * CH_T + (size_t)n * CH_S + 16 * q + tid;
        *reinterpret_cast<unsigned*>(&out[2 * j]) = pack_bf16x2(hi, hr);
    }

    if (tid >= GROUPS_PER_BLK) return;

    const int t0  = 1312 * q + (tid << 3);
    const int s00 = t0 / CH_M;
    const int m00 = t0 - s00 * CH_M;
    const int sHi = s00 + ((m00 + 7) >= CH_M ? 1 : 0);
    const int sLo = s00 - (m00 < 7 ? 1 : 0);          // -1 at t0=0 -> zeroed slot 0
    const int slotLo = sLo - 16 * q + 1;
    const int slotHi = sHi - 16 * q + 1;

    // Tap-row select: hi iff k - l >= delta (verified r17)
    const int delta = (m00 >= 75) ? (CH_M - m00) : (-m00);
    int thr[CH_L];
    #pragma unroll
    for (int l = 0; l < CH_L; ++l) thr[l] = l + delta;

    float2 flo[CH_L], fhi[CH_L];
    #pragma unroll
    for (int l = 0; l < CH_L; ++l) {
        flo[l] = tile[l][slotLo];
        fhi[l] = tile[l][slotHi];
    }

    const float* xrn = xr + (size_t)n * CH_T;
    const float* xin = xi + (size_t)n * CH_T;

    // window x[t0-8 .. t0+7] in registers
    float wr[16], wi[16];
    if (t0 == 0) {
        #pragma unroll
        for (int k = 0; k < 8; ++k) { wr[k] = 0.0f; wi[k] = 0.0f; }
        float4 a = *reinterpret_cast<const float4*>(xrn);
        float4 b = *reinterpret_cast<const float4*>(xrn + 4);
        wr[8]=a.x; wr[9]=a.y; wr[10]=a.z; wr[11]=a.w;
        wr[12]=b.x; wr[13]=b.y; wr[14]=b.z; wr[15]=b.w;
        a = *reinterpret_cast<const float4*>(xin);
        b = *reinterpret_cast<const float4*>(xin + 4);
        wi[8]=a.x; wi[9]=a.y; wi[10]=a.z; wi[11]=a.w;
        wi[12]=b.x; wi[13]=b.y; wi[14]=b.z; wi[15]=b.w;
    } else {
        const float* pr = xrn + t0 - 8;
        float4 a = *reinterpret_cast<const float4*>(pr);
        float4 b = *reinterpret_cast<const float4*>(pr + 4);
        float4 c = *reinterpret_cast<const float4*>(pr + 8);
        float4 d = *reinterpret_cast<const float4*>(pr + 12);
        wr[0]=a.x; wr[1]=a.y; wr[2]=a.z; wr[3]=a.w;
        wr[4]=b.x; wr[5]=b.y; wr[6]=b.z; wr[7]=b.w;
        wr[8]=c.x; wr[9]=c.y; wr[10]=c.z; wr[11]=c.w;
        wr[12]=d.x; wr[13]=d.y; wr[14]=d.z; wr[15]=d.w;
        const float* pi = xin + t0 - 8;
        a = *reinterpret_cast<const float4*>(pi);
        b = *reinterpret_cast<const float4*>(pi + 4);
        c = *reinterpret_cast<const float4*>(pi + 8);
        d = *reinterpret_cast<const float4*>(pi + 12);
        wi[0]=a.x; wi[1]=a.y; wi[2]=a.z; wi[3]=a.w;
        wi[4]=b.x; wi[5]=b.y; wi[6]=b.z; wi[7]=b.w;
        wi[8]=c.x; wi[9]=c.y; wi[10]=c.z; wi[11]=c.w;
        wi[12]=d.x; wi[13]=d.y; wi[14]=d.z; wi[15]=d.w;
    }

    uint4 v0, v1;
    #pragma unroll
    for (int k = 0; k < 8; ++k) {
        float ar = 0.0f, ai = 0.0f;
        #pragma unroll
        for (int l = 0; l < CH_L; ++l) {
            const bool hi = (k >= thr[l]);
            float cfx = hi ? fhi[l].x : flo[l].x;
            float cfy = hi ? fhi[l].y : flo[l].y;
            float vr  = wr[8 + k - l];
            float vi2 = wi[8 + k - l];
            ar += vr * cfx - vi2 * cfy;
            ai += vr * cfy + vi2 * cfx;
        }
        unsigned p = pack_bf16x2(ai * 0.125f, ar * 0.125f);
        if (k < 4) (&v0.x)[k] = p; else (&v1.x)[k - 4] = p;
    }

    size_t base = 2 * ((size_t)n * CH_T + t0);
    *reinterpret_cast<uint4*>(&out[base])     = v0;
    *reinterpret_cast<uint4*>(&out[base + 8]) = v1;
}

extern "C" void kernel_launch(void* const* d_in, const int* in_sizes, int n_in,
                              void* d_out, int out_size, void* d_ws, size_t ws_size,
                              hipStream_t stream) {
    const float* xr       = (const float*)d_in[0];
    const float* xi       = (const float*)d_in[1];
    const float* ray_u    = (const float*)d_in[2];
    const float* angles_u = (const float*)d_in[3];
    const float* phase_u  = (const float*)d_in[4];
    const void*  velocity = d_in[5];

    __hip_bfloat16* out = (__hip_bfloat16*)d_out;

    dim3 grid(CH_N, QSPLIT);
    channel_fused<<<grid, BLK, 0, stream>>>(xr, xi, ray_u, angles_u, phase_u,
                                            velocity, out);
}